// Round 7
// baseline (1886.107 us; speedup 1.0000x reference)
//
#include <hip/hip_runtime.h>
#include <hip/hip_bf16.h>

#define TT 1024
#define BB 512

typedef _Float16 half_t;
typedef __attribute__((ext_vector_type(8))) _Float16 v8h;
typedef __attribute__((ext_vector_type(4))) _Float16 v4hh;
typedef __attribute__((ext_vector_type(4))) float v4f;

__device__ __forceinline__ float sigf(float x) {
    return __builtin_amdgcn_rcpf(1.0f + __expf(-x));
}
__device__ __forceinline__ float tanhfast(float x) {
    return fmaf(2.0f, __builtin_amdgcn_rcpf(1.0f + __expf(-2.0f * x)), -1.0f);
}

// Drain ONLY lgkmcnt (LDS) — global loads/stores stay in flight.
__device__ __forceinline__ void barrier_lds_only() {
    asm volatile("s_waitcnt lgkmcnt(0)\n\ts_barrier" ::: "memory");
}

// ---------------- weight fp32 -> packed fp16 rows of 192 (128 ih | 64 hh) ----
__global__ __launch_bounds__(256)
void cvt_w(const float* __restrict__ w_ih, const float* __restrict__ w_hh,
           half_t* __restrict__ w16)
{
    const int id = blockIdx.x * 256 + threadIdx.x;  // 1024 rows * 192
    const int row = id / 192, k = id % 192;
    const float v = (k < 128) ? w_ih[row * 128 + k] : w_hh[row * 64 + (k - 128)];
    w16[id] = (half_t)v;
}

// ---------------- gx GEMM: gx[dir][bt][g] = in[bt][:] . W_ih[wrow][g][:] ----
// NW=8 (l1: 512 thr, waves = dir*4+gt, fp32 input) or NW=4 (l2: 256 thr, gt).
// grid 256 blocks; each block: 128 M-tiles of 16 rows; x-tile double-buffered
// in LDS; B-fragments (wave's 64 cols x K=128) in registers; C stored fp16.
template<bool IN_F16, int NW>
__global__ __launch_bounds__(NW * 64, 1)
void gemm_gx(const void* __restrict__ in_v, const half_t* __restrict__ w16,
             int wrow_base, half_t* __restrict__ gx)
{
    const int tid = threadIdx.x;
    const int w = tid >> 6;
    const int dir = (NW == 8) ? (w >> 2) : 0;
    const int gt  = (NW == 8) ? (w & 3) : w;
    const int l = tid & 63, q = l >> 4, n16 = l & 15;
    const int wrow = wrow_base + dir;

    __shared__ __align__(16) half_t xls[2][16][144];  // pad 144: 4-way max on b128

    // B-frags: wb2[ct][kt], B[k][n16] = W[wrow][gt*64+ct*16+n16][k], k=kt*32+q*8+e
    v8h wb2[4][4];
    #pragma unroll
    for (int ct = 0; ct < 4; ++ct) {
        const int c = gt * 64 + ct * 16 + n16;
        const half_t* p = w16 + ((size_t)(wrow * 256 + c)) * 192 + q * 8;
        #pragma unroll
        for (int kt = 0; kt < 4; ++kt) wb2[ct][kt] = *(const v8h*)(p + kt * 32);
    }

    half_t* gxd = gx + (size_t)dir * ((size_t)BB * TT * 256);

    const int tiles = (BB * TT) / (256 * 16);  // 128
    const size_t base = (size_t)blockIdx.x * tiles * 16;

    float4 sreg4;
    v8h sreg8;
    int srow, scol;
    if constexpr (!IN_F16) { srow = tid >> 5; scol = (tid & 31) * 4; }
    else                   { srow = tid >> 4; scol = (tid & 15) * 8; }

    auto stage_load = [&](int i) {
        const size_t bt = base + (size_t)i * 16 + srow;
        if constexpr (!IN_F16) sreg4 = *(const float4*)((const float*)in_v + bt * 128 + scol);
        else                   sreg8 = *(const v8h*)((const half_t*)in_v + bt * 128 + scol);
    };
    auto stage_write = [&](int buf) {
        if constexpr (!IN_F16) {
            v4hh t;
            t[0] = (half_t)sreg4.x; t[1] = (half_t)sreg4.y;
            t[2] = (half_t)sreg4.z; t[3] = (half_t)sreg4.w;
            *(v4hh*)&xls[buf][srow][scol] = t;
        } else {
            *(v8h*)&xls[buf][srow][scol] = sreg8;
        }
    };

    const v4f z4 = {0.f, 0.f, 0.f, 0.f};
    auto compute = [&](int buf, int i) {
        v8h af[4];
        #pragma unroll
        for (int kt = 0; kt < 4; ++kt) af[kt] = *(const v8h*)&xls[buf][n16][kt * 32 + q * 8];
        const size_t bt0 = base + (size_t)i * 16;
        #pragma unroll
        for (int ct = 0; ct < 4; ++ct) {
            v4f a = __builtin_amdgcn_mfma_f32_16x16x32_f16(af[0], wb2[ct][0], z4, 0, 0, 0);
            a = __builtin_amdgcn_mfma_f32_16x16x32_f16(af[1], wb2[ct][1], a, 0, 0, 0);
            a = __builtin_amdgcn_mfma_f32_16x16x32_f16(af[2], wb2[ct][2], a, 0, 0, 0);
            a = __builtin_amdgcn_mfma_f32_16x16x32_f16(af[3], wb2[ct][3], a, 0, 0, 0);
            const int col = gt * 64 + ct * 16 + n16;
            #pragma unroll
            for (int r = 0; r < 4; ++r)
                gxd[(bt0 + q * 4 + r) * 256 + col] = (half_t)a[r];  // C: col=lane&15, row=4q+r
        }
    };

    stage_load(0);
    stage_write(0);
    for (int i = 0; i < tiles; ++i) {
        if (i + 1 < tiles) stage_load(i + 1);
        barrier_lds_only();          // xls[i&1] visible to all waves
        compute(i & 1, i);
        if (i + 1 < tiles) stage_write((i + 1) & 1);  // waits vmcnt on sreg use only
    }
}

// ---------------- LSTM scan over precomputed gx: gates = gx_t + h @ W_hh^T --
// 1 block/CU. R=4 rows/block, row r -> MFMA A/C row 4r (cell state on lane
// group q==r, C-reg 0). 8 MFMAs/step (2 K-tiles x 4 gates). gx: 4 scalar fp16
// loads/lane/step, depth-3 register prefetch. h double-buffered in LDS.
template<int R, bool WRITE_SEQ, bool WRITE_LAST>
__global__ __launch_bounds__(256, 1)
void lstm_scan_g(const half_t* __restrict__ gx, const half_t* __restrict__ w16,
                 const float* __restrict__ b_ih, const float* __restrict__ b_hh,
                 int layer, int use_grid_dir,
                 half_t* __restrict__ out_seq, float* __restrict__ out_last)
{
    const int dir = use_grid_dir ? blockIdx.y : 0;
    const int wrow = layer * 2 + dir;
    const int col_off = dir * 64;
    const int b0 = blockIdx.x * R;
    const int wv = threadIdx.x >> 6;
    const int l  = threadIdx.x & 63;
    const int q  = l >> 4;
    const int n16 = l & 15;
    const int j = wv * 16 + n16;

    __shared__ __align__(16) half_t hs[2][16][72];
    {
        v8h z;
        #pragma unroll
        for (int e = 0; e < 8; ++e) z[e] = (half_t)0.f;
        ((v8h*)hs)[threadIdx.x] = z;
        if (threadIdx.x < 32) ((v8h*)hs)[256 + threadIdx.x] = z;
    }

    // W_hh B-frags: wb[gt][kh], B[k][n16] = Whh[gt*64+j][k], k = kh*32+q*8+e
    v8h wb[4][2];
    float bias[4];
    #pragma unroll
    for (int gt = 0; gt < 4; ++gt) {
        const int grow = wrow * 256 + gt * 64 + j;
        const half_t* p = w16 + (size_t)grow * 192 + 128 + q * 8;
        wb[gt][0] = *(const v8h*)(p);
        wb[gt][1] = *(const v8h*)(p + 32);
        bias[gt] = b_ih[grow] + b_hh[grow];
    }

    const long t0 = dir ? (TT - 1) : 0;
    const long gstep = dir ? -256 : 256;
    const long ostep = dir ? -128 : 128;

    const half_t* gxd = gx + (size_t)dir * ((size_t)BB * TT * 256);
    const half_t* gp = gxd + ((size_t)(b0 + q) * TT + t0) * 256 + j;

    half_t* op = nullptr;
    if constexpr (WRITE_SEQ) {
        op = out_seq + ((size_t)(b0 + q) * TT + t0) * 128 + col_off + j;
    }

    auto load_g = [&](half_t* d) {
        d[0] = gp[0]; d[1] = gp[64]; d[2] = gp[128]; d[3] = gp[192];
        gp += gstep;
    };

    float c = 0.f, hcur = 0.f;
    const v4f z4 = {0.f, 0.f, 0.f, 0.f};

    auto step = [&](const half_t (&g4)[4], int pb) {
        const v8h hf0 = *(const v8h*)&hs[pb][n16][q * 8];
        const v8h hf1 = *(const v8h*)&hs[pb][n16][32 + q * 8];
        float pre[4];
        #pragma unroll
        for (int gt = 0; gt < 4; ++gt) {
            v4f a = __builtin_amdgcn_mfma_f32_16x16x32_f16(hf0, wb[gt][0], z4, 0, 0, 0);
            a = __builtin_amdgcn_mfma_f32_16x16x32_f16(hf1, wb[gt][1], a, 0, 0, 0);
            pre[gt] = a[0] + ((float)g4[gt] + bias[gt]);
        }
        const float iv = sigf(pre[0]);
        const float fv = sigf(pre[1]);
        const float gv = tanhfast(pre[2]);
        const float ov = sigf(pre[3]);
        c = fv * c + iv * gv;
        const float h = ov * tanhfast(c);
        if (q < R) {
            const half_t h16 = (half_t)h;
            hs[pb ^ 1][4 * q][j] = h16;
            if constexpr (WRITE_SEQ) { *op = h16; op += ostep; }
            hcur = h;
        }
    };

    // depth-3 register prefetch of gx
    half_t g0[4], g1[4], g2[4], g3[4];
    load_g(g0);
    load_g(g1);
    load_g(g2);
    barrier_lds_only();  // hs zero-init visible

    for (int tt = 0; tt < TT; tt += 4) {
        if (tt + 3 < TT) load_g(g3);
        step(g0, 0); barrier_lds_only();
        if (tt + 4 < TT) load_g(g0);
        step(g1, 1); barrier_lds_only();
        if (tt + 5 < TT) load_g(g1);
        step(g2, 0); barrier_lds_only();
        if (tt + 6 < TT) load_g(g2);
        step(g3, 1); barrier_lds_only();
    }

    if constexpr (WRITE_LAST) {
        if (q < R) out_last[(size_t)(b0 + q) * 64 + j] = hcur;
    }
}

// ================= fallback (R6) path =================
template<int R, bool IN_F32, bool W16, bool WRITE_SEQ, bool WRITE_LAST>
__global__ __launch_bounds__(256, 1)
void lstm_scan_full(const void* __restrict__ in_v, const half_t* __restrict__ w16,
                    const float* __restrict__ w_ih, const float* __restrict__ w_hh,
                    const float* __restrict__ b_ih, const float* __restrict__ b_hh,
                    int layer, int use_grid_dir,
                    half_t* __restrict__ out_seq, float* __restrict__ out_last)
{
    const int dir = use_grid_dir ? blockIdx.y : 0;
    const int wrow = layer * 2 + dir;
    const int col_off = dir * 64;
    const int b0 = blockIdx.x * R;
    const int wv = threadIdx.x >> 6;
    const int l  = threadIdx.x & 63;
    const int q  = l >> 4;
    const int n16 = l & 15;
    const int j = wv * 16 + n16;
    const int rowc = ((n16 >> 2) < R) ? (n16 >> 2) : (R - 1);

    __shared__ __align__(16) half_t hs[2][16][72];
    {
        v8h z;
        #pragma unroll
        for (int e = 0; e < 8; ++e) z[e] = (half_t)0.f;
        ((v8h*)hs)[threadIdx.x] = z;
        if (threadIdx.x < 32) ((v8h*)hs)[256 + threadIdx.x] = z;
    }

    v8h wb[4][6];
    float bias[4];
    #pragma unroll
    for (int gt = 0; gt < 4; ++gt) {
        const int grow = wrow * 256 + gt * 64 + j;
        if constexpr (W16) {
            const half_t* p = w16 + (size_t)grow * 192 + q * 8;
            #pragma unroll
            for (int kt = 0; kt < 6; ++kt) wb[gt][kt] = *(const v8h*)(p + kt * 32);
        } else {
            const float* pih = w_ih + (size_t)grow * 128 + q * 8;
            #pragma unroll
            for (int kt = 0; kt < 4; ++kt) {
                const float4 a = *(const float4*)(pih + kt * 32);
                const float4 b = *(const float4*)(pih + kt * 32 + 4);
                v8h f;
                f[0] = (half_t)a.x; f[1] = (half_t)a.y; f[2] = (half_t)a.z; f[3] = (half_t)a.w;
                f[4] = (half_t)b.x; f[5] = (half_t)b.y; f[6] = (half_t)b.z; f[7] = (half_t)b.w;
                wb[gt][kt] = f;
            }
            const float* phh = w_hh + (size_t)grow * 64 + q * 8;
            #pragma unroll
            for (int kt = 0; kt < 2; ++kt) {
                const float4 a = *(const float4*)(phh + kt * 32);
                const float4 b = *(const float4*)(phh + kt * 32 + 4);
                v8h f;
                f[0] = (half_t)a.x; f[1] = (half_t)a.y; f[2] = (half_t)a.z; f[3] = (half_t)a.w;
                f[4] = (half_t)b.x; f[5] = (half_t)b.y; f[6] = (half_t)b.z; f[7] = (half_t)b.w;
                wb[gt][4 + kt] = f;
            }
        }
        bias[gt] = b_ih[grow] + b_hh[grow];
    }

    const long t0 = dir ? (TT - 1) : 0;
    const long xstep = dir ? -128 : 128;

    const float*  xp32 = nullptr;
    const half_t* xp16 = nullptr;
    if constexpr (IN_F32) xp32 = (const float*)in_v + ((size_t)(b0 + rowc) * TT + t0) * 128 + q * 8;
    else                  xp16 = (const half_t*)in_v + ((size_t)(b0 + rowc) * TT + t0) * 128 + q * 8;

    half_t* op = nullptr;
    if constexpr (WRITE_SEQ) {
        const int qr = (q < R) ? q : (R - 1);
        op = out_seq + ((size_t)(b0 + qr) * TT + t0) * 128 + col_off + j;
    }

    auto load_x = [&](v8h* dst) {
        if constexpr (IN_F32) {
            #pragma unroll
            for (int kt = 0; kt < 4; ++kt) {
                const float4 a = *(const float4*)(xp32 + kt * 32);
                const float4 b = *(const float4*)(xp32 + kt * 32 + 4);
                v8h f;
                f[0] = (half_t)a.x; f[1] = (half_t)a.y; f[2] = (half_t)a.z; f[3] = (half_t)a.w;
                f[4] = (half_t)b.x; f[5] = (half_t)b.y; f[6] = (half_t)b.z; f[7] = (half_t)b.w;
                dst[kt] = f;
            }
        } else {
            #pragma unroll
            for (int kt = 0; kt < 4; ++kt) dst[kt] = *(const v8h*)(xp16 + kt * 32);
        }
    };
    auto adv_x = [&]() { if constexpr (IN_F32) xp32 += xstep; else xp16 += xstep; };

    float c = 0.f, hcur = 0.f;
    const v4f z4 = {0.f, 0.f, 0.f, 0.f};

    auto step = [&](const v8h (&xf)[4], int pb) {
        const v8h hf0 = *(const v8h*)&hs[pb][n16][q * 8];
        const v8h hf1 = *(const v8h*)&hs[pb][n16][32 + q * 8];
        float pre[4];
        #pragma unroll
        for (int gt = 0; gt < 4; ++gt) {
            v4f a = __builtin_amdgcn_mfma_f32_16x16x32_f16(xf[0], wb[gt][0], z4, 0, 0, 0);
            a = __builtin_amdgcn_mfma_f32_16x16x32_f16(xf[1], wb[gt][1], a, 0, 0, 0);
            a = __builtin_amdgcn_mfma_f32_16x16x32_f16(hf0,   wb[gt][4], a, 0, 0, 0);
            v4f b = __builtin_amdgcn_mfma_f32_16x16x32_f16(xf[2], wb[gt][2], z4, 0, 0, 0);
            b = __builtin_amdgcn_mfma_f32_16x16x32_f16(xf[3], wb[gt][3], b, 0, 0, 0);
            b = __builtin_amdgcn_mfma_f32_16x16x32_f16(hf1,   wb[gt][5], b, 0, 0, 0);
            pre[gt] = a[0] + b[0] + bias[gt];
        }
        const float iv = sigf(pre[0]);
        const float fv = sigf(pre[1]);
        const float gv = tanhfast(pre[2]);
        const float ov = sigf(pre[3]);
        c = fv * c + iv * gv;
        const float h = ov * tanhfast(c);
        if (q < R) {
            const half_t h16 = (half_t)h;
            hs[pb ^ 1][4 * q][j] = h16;
            if constexpr (WRITE_SEQ) { *op = h16; op += xstep; }
            hcur = h;
        }
    };

    v8h x0[4], x1[4], x2[4], x3[4];
    load_x(x0); adv_x();
    load_x(x1); adv_x();
    load_x(x2); adv_x();
    barrier_lds_only();

    for (int tt = 0; tt < TT; tt += 4) {
        if (tt + 3 < TT) { load_x(x3); adv_x(); }
        step(x0, 0); barrier_lds_only();
        if (tt + 4 < TT) { load_x(x0); adv_x(); }
        step(x1, 1); barrier_lds_only();
        if (tt + 5 < TT) { load_x(x1); adv_x(); }
        step(x2, 0); barrier_lds_only();
        if (tt + 6 < TT) { load_x(x2); adv_x(); }
        step(x3, 1); barrier_lds_only();
    }

    if constexpr (WRITE_LAST) {
        if (q < R) out_last[(size_t)(b0 + q) * 64 + j] = hcur;
    }
}

// ---------------- x fp32 -> fp16 (fallback path) ----------------
__global__ __launch_bounds__(256)
void cvt_x(const float* __restrict__ in, half_t* __restrict__ out)
{
    const size_t i = ((size_t)blockIdx.x * 256 + threadIdx.x) * 8;
    const float4 a = *(const float4*)(in + i);
    const float4 b = *(const float4*)(in + i + 4);
    v8h f;
    f[0] = (half_t)a.x; f[1] = (half_t)a.y; f[2] = (half_t)a.z; f[3] = (half_t)a.w;
    f[4] = (half_t)b.x; f[5] = (half_t)b.y; f[6] = (half_t)b.z; f[7] = (half_t)b.w;
    *(v8h*)(out + i) = f;
}

// ---------------- Layer 2 backward (single step, h0=0) + FC ----------------
__global__ __launch_bounds__(256)
void l2bwd_fc(const half_t* __restrict__ in, const float* __restrict__ w_ih,
              const float* __restrict__ b_ih, const float* __restrict__ b_hh,
              const float* __restrict__ hlast, const float* __restrict__ fc_w,
              const float* __restrict__ fc_b, float* __restrict__ out)
{
    const int b = blockIdx.x;
    const int g = threadIdx.x;
    __shared__ float gpre[256];
    __shared__ float hb[64];

    float acc = b_ih[3 * 256 + g] + b_hh[3 * 256 + g];
    const float* wp = w_ih + ((size_t)(3 * 256 + g)) * 128;
    const half_t* xp = in + ((size_t)b * TT + (TT - 1)) * 128;
    #pragma unroll
    for (int k = 0; k < 128; k += 8) {
        const float4 w0 = *(const float4*)(wp + k);
        const float4 w1 = *(const float4*)(wp + k + 4);
        const v8h xv = *(const v8h*)(xp + k);
        acc = fmaf(w0.x, (float)xv[0], acc); acc = fmaf(w0.y, (float)xv[1], acc);
        acc = fmaf(w0.z, (float)xv[2], acc); acc = fmaf(w0.w, (float)xv[3], acc);
        acc = fmaf(w1.x, (float)xv[4], acc); acc = fmaf(w1.y, (float)xv[5], acc);
        acc = fmaf(w1.z, (float)xv[6], acc); acc = fmaf(w1.w, (float)xv[7], acc);
    }
    gpre[g] = acc;
    __syncthreads();

    if (g < 64) {
        const float i  = sigf(gpre[g]);
        const float gg = tanhfast(gpre[128 + g]);
        const float o  = sigf(gpre[192 + g]);
        hb[g] = o * tanhfast(i * gg);
    }
    __syncthreads();

    if (g < 64) {
        float p = fc_w[g] * hlast[(size_t)b * 64 + g] + fc_w[64 + g] * hb[g];
        #pragma unroll
        for (int off = 32; off > 0; off >>= 1) p += __shfl_down(p, off);
        if (g == 0) out[b] = p + fc_b[0];
    }
}

extern "C" void kernel_launch(void* const* d_in, const int* in_sizes, int n_in,
                              void* d_out, int out_size, void* d_ws, size_t ws_size,
                              hipStream_t stream)
{
    const float* x    = (const float*)d_in[0];
    const float* w_ih = (const float*)d_in[1];
    const float* w_hh = (const float*)d_in[2];
    const float* b_ih = (const float*)d_in[3];
    const float* b_hh = (const float*)d_in[4];
    const float* fc_w = (const float*)d_in[5];
    const float* fc_b = (const float*)d_in[6];
    float* out = (float*)d_out;

    const size_t seq_b   = (size_t)BB * TT * 128 * sizeof(half_t);   // 128 MiB
    const size_t gx_b    = (size_t)2 * BB * TT * 256 * sizeof(half_t); // 512 MiB
    const size_t w16_b   = (size_t)1024 * 192 * sizeof(half_t);      // 384 KiB
    const size_t hlast_b = (size_t)BB * 64 * sizeof(float);          // 128 KiB

    if (ws_size >= w16_b + hlast_b + seq_b + gx_b) {
        // Tier A: [ w16 ][ hlast ][ out1 128MB ][ gx 512MB (l2 gx aliases) ]
        half_t* w16   = (half_t*)d_ws;
        float*  hlast = (float*)((char*)d_ws + w16_b);
        half_t* out1  = (half_t*)((char*)d_ws + w16_b + hlast_b);
        half_t* gx    = (half_t*)((char*)d_ws + w16_b + hlast_b + seq_b);

        cvt_w<<<768, 256, 0, stream>>>(w_ih, w_hh, w16);
        gemm_gx<false, 8><<<256, 512, 0, stream>>>(x, w16, 0, gx);
        lstm_scan_g<4, true, false><<<dim3(BB / 4, 2), 256, 0, stream>>>(
            gx, w16, b_ih, b_hh, 0, 1, out1, nullptr);
        gemm_gx<true, 4><<<256, 256, 0, stream>>>(out1, w16, 2, gx);
        lstm_scan_g<4, false, true><<<dim3(BB / 4, 1), 256, 0, stream>>>(
            gx, w16, b_ih, b_hh, 1, 0, nullptr, hlast);
        l2bwd_fc<<<BB, 256, 0, stream>>>(out1, w_ih, b_ih, b_hh, hlast, fc_w, fc_b, out);
    } else if (ws_size >= w16_b + hlast_b + 2 * seq_b) {
        // Tier B: R6 path
        half_t* w16   = (half_t*)d_ws;
        float*  hlast = (float*)((char*)d_ws + w16_b);
        half_t* x16   = (half_t*)((char*)d_ws + w16_b + hlast_b);
        half_t* out1  = (half_t*)((char*)d_ws + w16_b + hlast_b + seq_b);

        cvt_w<<<768, 256, 0, stream>>>(w_ih, w_hh, w16);
        cvt_x<<<(BB * TT * 128 / 8) / 256, 256, 0, stream>>>(x, x16);
        lstm_scan_full<4, false, true, true, false><<<dim3(BB / 4, 2), 256, 0, stream>>>(
            x16, w16, w_ih, w_hh, b_ih, b_hh, 0, 1, out1, nullptr);
        lstm_scan_full<4, false, true, false, true><<<dim3(BB / 4, 1), 256, 0, stream>>>(
            out1, w16, w_ih, w_hh, b_ih, b_hh, 1, 0, nullptr, hlast);
        l2bwd_fc<<<BB, 256, 0, stream>>>(out1, w_ih, b_ih, b_hh, hlast, fc_w, fc_b, out);
    } else {
        // Tier C: minimal workspace
        half_t* out1  = (half_t*)d_ws;
        float*  hlast = (float*)((char*)d_ws + seq_b);

        lstm_scan_full<4, true, false, true, false><<<dim3(BB / 4, 2), 256, 0, stream>>>(
            x, nullptr, w_ih, w_hh, b_ih, b_hh, 0, 1, out1, nullptr);
        lstm_scan_full<4, false, false, false, true><<<dim3(BB / 4, 1), 256, 0, stream>>>(
            out1, nullptr, w_ih, w_hh, b_ih, b_hh, 1, 0, nullptr, hlast);
        l2bwd_fc<<<BB, 256, 0, stream>>>(out1, w_ih, b_ih, b_hh, hlast, fc_w, fc_b, out);
    }
}